// Round 19
// baseline (50.435 us; speedup 1.0000x reference)
//
#include <hip/hip_runtime.h>
#include <cstddef>

#define HDIM 2048
#define NE 64
#define TOPK 4

typedef short bf16x8 __attribute__((ext_vector_type(8)));
typedef float f32x4 __attribute__((ext_vector_type(4)));

// Exact 3-way bf16 truncation split: a = f(h0) + f(h1) + f(h2) (24 mantissa bits).
__device__ __forceinline__ void split3(float a, unsigned short& h0,
                                       unsigned short& h1, unsigned short& h2) {
    unsigned int u = __float_as_uint(a);
    h0 = (unsigned short)(u >> 16);
    float f0 = __uint_as_float(u & 0xffff0000u);
    float r1 = a - f0;
    unsigned int v = __float_as_uint(r1);
    h1 = (unsigned short)(v >> 16);
    float f1 = __uint_as_float(v & 0xffff0000u);
    float r2 = r1 - f1;
    h2 = (unsigned short)(__float_as_uint(r2) >> 16);
}

// ---------- prepass (r16-proven, unchanged): B fragments, 3 bf16 planes ----------
// wtb[plane][s(64)][n(4)][lane(64)][j(8)]: e = 16n + (lane&15), k = 32s + 8*(lane>>4) + j
__global__ __launch_bounds__(256) void prep_b_kernel(
    const float* __restrict__ w, const float* __restrict__ scale,
    unsigned short* __restrict__ wtb)
{
    const int s = blockIdx.x;          // 0..63
    const int n = threadIdx.x >> 6;    // 0..3
    const int l = threadIdx.x & 63;
    const int e = 16 * n + (l & 15);
    const int k = 32 * s + 8 * (l >> 4);
    unsigned short h0[8], h1[8], h2[8];
    #pragma unroll
    for (int j = 0; j < 8; ++j) {
        float v = w[(size_t)e * HDIM + k + j] * scale[k + j];
        split3(v, h0[j], h1[j], h2[j]);
    }
    size_t off = ((size_t)s * 4 + n) * 512 + (size_t)l * 8;
    #pragma unroll
    for (int j = 0; j < 8; ++j) {
        wtb[off + j]          = h0[j];
        wtb[131072 + off + j] = h1[j];
        wtb[262144 + off + j] = h2[j];
    }
}

// ---------- fused: register-slim waves at 4 waves/SIMD (16 waves/CU) ----------
// Block = 32 tokens, 512 thr = 8 waves = K-eighths; grid 512 -> 2 blocks/CU.
// Per wave: 32 tok x 64 exp x 256 K (2 A-tiles per B set). B single-buffered
// (latency covered by 3 partner waves); A reg-dbuf. ~120 VGPR live set.
__global__ __launch_bounds__(512, 2) void fused_router_kernel(
    const float* __restrict__ x, const unsigned short* __restrict__ wtb,
    const float* __restrict__ pes,
    float* __restrict__ probs, float* __restrict__ tkw, float* __restrict__ tki)
{
    __shared__ float Sp[8][32 * 65];   // per-kh score partials (66.5 KB)
    __shared__ float Pl[32 * 65];
    __shared__ float SQp[8][32];
    __shared__ float FN[32];
    __shared__ float RS[32];

    const int tid = threadIdx.x;
    const int kh = tid >> 6;           // K-eighth 0..7
    const int l = tid & 63;
    const int tok0 = blockIdx.x * 32;
    const int m = l & 15;              // A row / B col within tile
    const int g = l >> 4;              // k-group

    const float* xr0 = x + (size_t)(tok0 + m) * HDIM + 256 * kh + 8 * g;   // tile 0
    const float* xr1 = xr0 + (size_t)16 * HDIM;                             // tile 1
    const unsigned short* wb = wtb + (size_t)(8 * kh) * 2048 + (size_t)l * 8;

    f32x4 acc0[4], acc1[4];
    #pragma unroll
    for (int n = 0; n < 4; ++n) {
        acc0[n] = (f32x4){0.f, 0.f, 0.f, 0.f};
        acc1[n] = (f32x4){0.f, 0.f, 0.f, 0.f};
    }
    float ssq0 = 0.f, ssq1 = 0.f;

    float4 Aq[2][4];                   // A dbuf: [buf][tile*2 + half]
    bf16x8 Bb[12];                     // B single buffer [3n+plane]

#define LOADA(buf, s) { \
        Aq[buf][0] = *(const float4*)(xr0 + 32 * (s)); \
        Aq[buf][1] = *(const float4*)(xr0 + 32 * (s) + 4); \
        Aq[buf][2] = *(const float4*)(xr1 + 32 * (s)); \
        Aq[buf][3] = *(const float4*)(xr1 + 32 * (s) + 4); }
#define LOADB(s) { \
        const unsigned short* bs_ = wb + (size_t)(s) * 2048; \
        _Pragma("unroll") \
        for (int n = 0; n < 4; ++n) { \
            Bb[3*n + 0] = *(const bf16x8*)(bs_ + n * 512); \
            Bb[3*n + 1] = *(const bf16x8*)(bs_ + n * 512 + 131072); \
            Bb[3*n + 2] = *(const bf16x8*)(bs_ + n * 512 + 262144); } }

    LOADA(0, 0);

    #pragma unroll
    for (int s = 0; s < 8; ++s) {
        const int cur = s & 1, nxt = cur ^ 1;
        LOADB(s);                                  // single-buffer: TLP covers L2 latency
        if (s + 1 < 8) LOADA(nxt, s + 1);          // next A kstep in flight (HBM)

        float af0[8], af1[8];
        *(float4*)af0 = Aq[cur][0]; *(float4*)(af0 + 4) = Aq[cur][1];
        *(float4*)af1 = Aq[cur][2]; *(float4*)(af1 + 4) = Aq[cur][3];
        unsigned short p0[8], p1[8], p2[8], q0[8], q1[8], q2[8];
        #pragma unroll
        for (int j = 0; j < 8; ++j) {
            split3(af0[j], p0[j], p1[j], p2[j]);
            split3(af1[j], q0[j], q1[j], q2[j]);
            ssq0 = fmaf(af0[j], af0[j], ssq0);
            ssq1 = fmaf(af1[j], af1[j], ssq1);
        }
        bf16x8 a0, a1, a2, c0, c1, c2;
        #pragma unroll
        for (int j = 0; j < 8; ++j) {
            a0[j] = (short)p0[j]; a1[j] = (short)p1[j]; a2[j] = (short)p2[j];
            c0[j] = (short)q0[j]; c1[j] = (short)q1[j]; c2[j] = (short)q2[j];
        }
        #pragma unroll
        for (int n = 0; n < 4; ++n) {
            bf16x8 b0 = Bb[3*n + 0];
            bf16x8 b1 = Bb[3*n + 1];
            bf16x8 b2 = Bb[3*n + 2];
            acc0[n] = __builtin_amdgcn_mfma_f32_16x16x32_bf16(a0, b0, acc0[n], 0, 0, 0);
            acc0[n] = __builtin_amdgcn_mfma_f32_16x16x32_bf16(a0, b1, acc0[n], 0, 0, 0);
            acc0[n] = __builtin_amdgcn_mfma_f32_16x16x32_bf16(a1, b0, acc0[n], 0, 0, 0);
            acc0[n] = __builtin_amdgcn_mfma_f32_16x16x32_bf16(a1, b1, acc0[n], 0, 0, 0);
            acc0[n] = __builtin_amdgcn_mfma_f32_16x16x32_bf16(a0, b2, acc0[n], 0, 0, 0);
            acc0[n] = __builtin_amdgcn_mfma_f32_16x16x32_bf16(a2, b0, acc0[n], 0, 0, 0);
            acc1[n] = __builtin_amdgcn_mfma_f32_16x16x32_bf16(c0, b0, acc1[n], 0, 0, 0);
            acc1[n] = __builtin_amdgcn_mfma_f32_16x16x32_bf16(c0, b1, acc1[n], 0, 0, 0);
            acc1[n] = __builtin_amdgcn_mfma_f32_16x16x32_bf16(c1, b0, acc1[n], 0, 0, 0);
            acc1[n] = __builtin_amdgcn_mfma_f32_16x16x32_bf16(c1, b1, acc1[n], 0, 0, 0);
            acc1[n] = __builtin_amdgcn_mfma_f32_16x16x32_bf16(c0, b2, acc1[n], 0, 0, 0);
            acc1[n] = __builtin_amdgcn_mfma_f32_16x16x32_bf16(c2, b0, acc1[n], 0, 0, 0);
        }
    }
#undef LOADA
#undef LOADB

    // ssq: sum the 4 k-group lanes per token (lanes differ in bits 4,5)
    ssq0 += __shfl_xor(ssq0, 16, 64);
    ssq0 += __shfl_xor(ssq0, 32, 64);
    ssq1 += __shfl_xor(ssq1, 16, 64);
    ssq1 += __shfl_xor(ssq1, 32, 64);

    // ---- stage partials ----
    #pragma unroll
    for (int n = 0; n < 4; ++n)
        #pragma unroll
        for (int r = 0; r < 4; ++r) {   // D: col=lane&15, row=4*(lane>>4)+reg [m89]
            Sp[kh][(4 * g + r) * 65 + 16 * n + m]      = acc0[n][r];
            Sp[kh][(16 + 4 * g + r) * 65 + 16 * n + m] = acc1[n][r];
        }
    if (l < 16) {
        SQp[kh][m]      = ssq0;
        SQp[kh][16 + m] = ssq1;
    }
    __syncthreads();

    if (tid < 32) {
        float q0 = (SQp[0][tid] + SQp[1][tid]) + (SQp[2][tid] + SQp[3][tid]);
        float q1 = (SQp[4][tid] + SQp[5][tid]) + (SQp[6][tid] + SQp[7][tid]);
        FN[tid] = rsqrtf((q0 + q1) * (1.0f / HDIM) + 1e-6f) * 0.022097086912079612f;
    }
    __syncthreads();

    {   // combine 8 partials in place: 512 float4, one per thread
        int f = tid;
        int mr = f >> 4;
        int e4 = (f & 15) * 4;
        int base = mr * 65 + e4;
        float4 t0 = *(const float4*)&Sp[0][base];
        float4 t1 = *(const float4*)&Sp[1][base];
        float4 t2 = *(const float4*)&Sp[2][base];
        float4 t3 = *(const float4*)&Sp[3][base];
        float4 t4 = *(const float4*)&Sp[4][base];
        float4 t5 = *(const float4*)&Sp[5][base];
        float4 t6 = *(const float4*)&Sp[6][base];
        float4 t7 = *(const float4*)&Sp[7][base];
        float fn = FN[mr];
        float4 sv;
        sv.x = (((t0.x + t1.x) + (t2.x + t3.x)) + ((t4.x + t5.x) + (t6.x + t7.x))) * fn;
        sv.y = (((t0.y + t1.y) + (t2.y + t3.y)) + ((t4.y + t5.y) + (t6.y + t7.y))) * fn;
        sv.z = (((t0.z + t1.z) + (t2.z + t3.z)) + ((t4.z + t5.z) + (t6.z + t7.z))) * fn;
        sv.w = (((t0.w + t1.w) + (t2.w + t3.w)) + ((t4.w + t5.w) + (t6.w + t7.w))) * fn;
        *(float4*)&Sp[0][base] = sv;    // Sl == Sp[0]
    }
    __syncthreads();

    float* Sl = &Sp[0][0];

    // ---- proven epilogue (32 tokens) ----
    if (tid < 32) {
        const int mm = tid;
        float mx = -3.0e38f;
        for (int e = 0; e < NE; e++) mx = fmaxf(mx, Sl[mm * 65 + e]);
        float sum = 0.f;
        for (int e = 0; e < NE; e++) {
            float p = __expf(Sl[mm * 65 + e] - mx);
            Pl[mm * 65 + e] = p;
            sum += p;
        }
        RS[mm] = 1.0f / sum;
    }
    __syncthreads();

    {   // coalesced probs write: 512 float4, one per thread
        int f = tid;
        int mr = f >> 4;
        int e0 = (f & 15) * 4;
        float rs = RS[mr];
        float4 pv;
        pv.x = Pl[mr * 65 + e0 + 0] * rs;
        pv.y = Pl[mr * 65 + e0 + 1] * rs;
        pv.z = Pl[mr * 65 + e0 + 2] * rs;
        pv.w = Pl[mr * 65 + e0 + 3] * rs;
        *(float4*)&probs[(size_t)(tok0 + mr) * NE + e0] = pv;
    }

    if (tid < 32) {                      // destructive top-4, lowest-index ties
        const int mm = tid;
        float wvv[TOPK]; int idx[TOPK];
        float wsum = 0.f;
        #pragma unroll
        for (int kk = 0; kk < TOPK; ++kk) {
            float best = -3.0e38f; int bi = 0;
            for (int e = 0; e < NE; e++) {
                float v = Sl[mm * 65 + e];
                if (v > best) { best = v; bi = e; }
            }
            Sl[mm * 65 + bi] = -3.4e38f;
            float p = Pl[mm * 65 + bi];
            wvv[kk] = p; idx[kk] = bi; wsum += p;
        }
        float inv = 1.0f / wsum;
        size_t ob = (size_t)(tok0 + mm) * TOPK;
        #pragma unroll
        for (int kk = 0; kk < TOPK; kk++) {
            tkw[ob + kk] = wvv[kk] * inv * pes[idx[kk]];
            tki[ob + kk] = (float)idx[kk];   // harness reads flat buffer as float32
        }
    }
}

extern "C" void kernel_launch(void* const* d_in, const int* in_sizes, int n_in,
                              void* d_out, int out_size, void* d_ws, size_t ws_size,
                              hipStream_t stream) {
    const float* x     = (const float*)d_in[0];
    const float* w     = (const float*)d_in[1];
    const float* scale = (const float*)d_in[2];
    const float* pes   = (const float*)d_in[3];
    const int tokens = in_sizes[0] / HDIM;      // 16384

    float* probs = (float*)d_out;
    float* tkw   = probs + (size_t)tokens * NE;
    float* tki   = tkw + (size_t)tokens * TOPK;

    unsigned short* wtb = (unsigned short*)d_ws;   // 3 planes x 256 KB = 768 KB

    prep_b_kernel<<<HDIM / 32, 256, 0, stream>>>(w, scale, wtb);

    const int grid = tokens / 32;               // 512 -> 2 blocks/CU, 16 waves/CU
    fused_router_kernel<<<grid, 512, 0, stream>>>(x, wtb, pes, probs, tkw, tki);
}

// Round 20
// 44.950 us; speedup vs baseline: 1.1220x; 1.1220x over previous
//
#include <hip/hip_runtime.h>
#include <cstddef>

#define HDIM 2048
#define NE 64
#define TOPK 4

typedef short bf16x8 __attribute__((ext_vector_type(8)));
typedef float f32x4 __attribute__((ext_vector_type(4)));

// Exact 3-way bf16 truncation split: a = f(h0) + f(h1) + f(h2) (24 mantissa bits).
__device__ __forceinline__ void split3(float a, unsigned short& h0,
                                       unsigned short& h1, unsigned short& h2) {
    unsigned int u = __float_as_uint(a);
    h0 = (unsigned short)(u >> 16);
    float f0 = __uint_as_float(u & 0xffff0000u);
    float r1 = a - f0;
    unsigned int v = __float_as_uint(r1);
    h1 = (unsigned short)(v >> 16);
    float f1 = __uint_as_float(v & 0xffff0000u);
    float r2 = r1 - f1;
    h2 = (unsigned short)(__float_as_uint(r2) >> 16);
}

// ---------- prepass (r16-proven, unchanged): B fragments, 3 bf16 planes ----------
// wtb[plane][s(64)][n(4)][lane(64)][j(8)]: e = 16n + (lane&15), k = 32s + 8*(lane>>4) + j
__global__ __launch_bounds__(256) void prep_b_kernel(
    const float* __restrict__ w, const float* __restrict__ scale,
    unsigned short* __restrict__ wtb)
{
    const int s = blockIdx.x;          // 0..63
    const int n = threadIdx.x >> 6;    // 0..3
    const int l = threadIdx.x & 63;
    const int e = 16 * n + (l & 15);
    const int k = 32 * s + 8 * (l >> 4);
    unsigned short h0[8], h1[8], h2[8];
    #pragma unroll
    for (int j = 0; j < 8; ++j) {
        float v = w[(size_t)e * HDIM + k + j] * scale[k + j];
        split3(v, h0[j], h1[j], h2[j]);
    }
    size_t off = ((size_t)s * 4 + n) * 512 + (size_t)l * 8;
    #pragma unroll
    for (int j = 0; j < 8; ++j) {
        wtb[off + j]          = h0[j];
        wtb[131072 + off + j] = h1[j];
        wtb[262144 + off + j] = h2[j];
    }
}

// ---------- fused: r18 structure (M=64/wave, 1 block/CU), pressure-tuned ----------
// Deltas vs r18: (1) next-B load split into two 6-frag halves after tiles 0/2
// (peak B live 24->18 frags, -24 VGPR, same >=1-tile latency cover);
// (2) A (HBM) load issued first each kstep; (3) s_setprio around MFMA clusters
// (barrier-free independent waves = the attn-like regime where T5 pays).
__global__ __launch_bounds__(512, 1) void fused_router_kernel(
    const float* __restrict__ x, const unsigned short* __restrict__ wtb,
    const float* __restrict__ pes,
    float* __restrict__ probs, float* __restrict__ tkw, float* __restrict__ tki)
{
    __shared__ float Sp[8][64 * 65];   // per-kh score partials (combined in place into Sp[0])
    __shared__ float Pl[64 * 65];
    __shared__ float SQp[8][64];
    __shared__ float FN[64];
    __shared__ float RS[64];

    const int tid = threadIdx.x;
    const int kh = tid >> 6;           // K-eighth 0..7
    const int l = tid & 63;
    const int tok0 = blockIdx.x * 64;
    const int m = l & 15;              // A row / B col within tile
    const int g = l >> 4;              // k-group

    const float* xr0 = x + (size_t)(tok0 + m) * HDIM + 256 * kh + 8 * g;   // tile 0
    const unsigned short* wb = wtb + (size_t)(8 * kh) * 2048 + (size_t)l * 8;

    f32x4 acc[4][4];                   // [tile][n]
    #pragma unroll
    for (int t = 0; t < 4; ++t)
        #pragma unroll
        for (int n = 0; n < 4; ++n) acc[t][n] = (f32x4){0.f, 0.f, 0.f, 0.f};
    float ssq[4] = {0.f, 0.f, 0.f, 0.f};

    float4 Aq[2][8];                   // [buf][tile*2 + half]
    bf16x8 Bb[2][12];                  // [buf][3n+plane]

#define LOADA(buf, s) { _Pragma("unroll") \
        for (int t = 0; t < 4; ++t) { \
            Aq[buf][2*t]     = *(const float4*)(xr0 + (size_t)(16*t) * HDIM + 32 * (s)); \
            Aq[buf][2*t + 1] = *(const float4*)(xr0 + (size_t)(16*t) * HDIM + 32 * (s) + 4); } }
#define LOADB_LO(buf, s) { \
        const unsigned short* bs_ = wb + (size_t)(s) * 2048; \
        _Pragma("unroll") \
        for (int n = 0; n < 2; ++n) { \
            Bb[buf][3*n + 0] = *(const bf16x8*)(bs_ + n * 512); \
            Bb[buf][3*n + 1] = *(const bf16x8*)(bs_ + n * 512 + 131072); \
            Bb[buf][3*n + 2] = *(const bf16x8*)(bs_ + n * 512 + 262144); } }
#define LOADB_HI(buf, s) { \
        const unsigned short* bs_ = wb + (size_t)(s) * 2048; \
        _Pragma("unroll") \
        for (int n = 2; n < 4; ++n) { \
            Bb[buf][3*n + 0] = *(const bf16x8*)(bs_ + n * 512); \
            Bb[buf][3*n + 1] = *(const bf16x8*)(bs_ + n * 512 + 131072); \
            Bb[buf][3*n + 2] = *(const bf16x8*)(bs_ + n * 512 + 262144); } }
#define TILE(tt, cur) { \
        float af[8]; \
        *(float4*)af = Aq[cur][2*(tt)]; *(float4*)(af + 4) = Aq[cur][2*(tt) + 1]; \
        unsigned short p0[8], p1[8], p2[8]; \
        _Pragma("unroll") \
        for (int j = 0; j < 8; ++j) { \
            split3(af[j], p0[j], p1[j], p2[j]); \
            ssq[tt] = fmaf(af[j], af[j], ssq[tt]); \
        } \
        bf16x8 a0, a1, a2; \
        _Pragma("unroll") \
        for (int j = 0; j < 8; ++j) { \
            a0[j] = (short)p0[j]; a1[j] = (short)p1[j]; a2[j] = (short)p2[j]; \
        } \
        __builtin_amdgcn_s_setprio(1); \
        _Pragma("unroll") \
        for (int n = 0; n < 4; ++n) { \
            bf16x8 b0 = Bb[cur][3*n + 0]; \
            bf16x8 b1 = Bb[cur][3*n + 1]; \
            bf16x8 b2 = Bb[cur][3*n + 2]; \
            acc[tt][n] = __builtin_amdgcn_mfma_f32_16x16x32_bf16(a0, b0, acc[tt][n], 0, 0, 0); \
            acc[tt][n] = __builtin_amdgcn_mfma_f32_16x16x32_bf16(a0, b1, acc[tt][n], 0, 0, 0); \
            acc[tt][n] = __builtin_amdgcn_mfma_f32_16x16x32_bf16(a1, b0, acc[tt][n], 0, 0, 0); \
            acc[tt][n] = __builtin_amdgcn_mfma_f32_16x16x32_bf16(a1, b1, acc[tt][n], 0, 0, 0); \
            acc[tt][n] = __builtin_amdgcn_mfma_f32_16x16x32_bf16(a0, b2, acc[tt][n], 0, 0, 0); \
            acc[tt][n] = __builtin_amdgcn_mfma_f32_16x16x32_bf16(a2, b0, acc[tt][n], 0, 0, 0); \
        } \
        __builtin_amdgcn_s_setprio(0); \
    }

    LOADA(0, 0);
    LOADB_LO(0, 0);
    LOADB_HI(0, 0);

    #pragma unroll
    for (int s = 0; s < 8; ++s) {
        const int cur = s & 1, nxt = cur ^ 1;
        if (s + 1 < 8) LOADA(nxt, s + 1);       // HBM A first: longest latency
        TILE(0, cur)
        if (s + 1 < 8) LOADB_LO(nxt, s + 1);    // 6 frags; peak B live 18 not 24
        TILE(1, cur)
        TILE(2, cur)
        if (s + 1 < 8) LOADB_HI(nxt, s + 1);
        TILE(3, cur)
    }
#undef LOADA
#undef LOADB_LO
#undef LOADB_HI
#undef TILE

    // ssq: sum the 4 k-group lanes per token (lanes differ in bits 4,5)
    #pragma unroll
    for (int t = 0; t < 4; ++t) {
        ssq[t] += __shfl_xor(ssq[t], 16, 64);
        ssq[t] += __shfl_xor(ssq[t], 32, 64);
    }

    // ---- stage partials ----
    #pragma unroll
    for (int t = 0; t < 4; ++t)
        #pragma unroll
        for (int n = 0; n < 4; ++n)
            #pragma unroll
            for (int r = 0; r < 4; ++r)   // D: col=lane&15, row=4*(lane>>4)+reg [m89]
                Sp[kh][(16*t + 4*g + r) * 65 + 16*n + m] = acc[t][n][r];
    if (l < 16) {
        #pragma unroll
        for (int t = 0; t < 4; ++t) SQp[kh][16*t + m] = ssq[t];
    }
    __syncthreads();

    if (tid < 64) {
        float q0 = (SQp[0][tid] + SQp[1][tid]) + (SQp[2][tid] + SQp[3][tid]);
        float q1 = (SQp[4][tid] + SQp[5][tid]) + (SQp[6][tid] + SQp[7][tid]);
        FN[tid] = rsqrtf((q0 + q1) * (1.0f / HDIM) + 1e-6f) * 0.022097086912079612f;
    }
    __syncthreads();

    #pragma unroll
    for (int qq = 0; qq < 2; qq++) {    // 1024 float4: combine 8 partials in place
        int f = tid + 512 * qq;
        int mr = f >> 4;
        int e4 = (f & 15) * 4;
        int base = mr * 65 + e4;
        float4 t0 = *(const float4*)&Sp[0][base];
        float4 t1 = *(const float4*)&Sp[1][base];
        float4 t2 = *(const float4*)&Sp[2][base];
        float4 t3 = *(const float4*)&Sp[3][base];
        float4 t4 = *(const float4*)&Sp[4][base];
        float4 t5 = *(const float4*)&Sp[5][base];
        float4 t6 = *(const float4*)&Sp[6][base];
        float4 t7 = *(const float4*)&Sp[7][base];
        float fn = FN[mr];
        float4 sv;
        sv.x = (((t0.x + t1.x) + (t2.x + t3.x)) + ((t4.x + t5.x) + (t6.x + t7.x))) * fn;
        sv.y = (((t0.y + t1.y) + (t2.y + t3.y)) + ((t4.y + t5.y) + (t6.y + t7.y))) * fn;
        sv.z = (((t0.z + t1.z) + (t2.z + t3.z)) + ((t4.z + t5.z) + (t6.z + t7.z))) * fn;
        sv.w = (((t0.w + t1.w) + (t2.w + t3.w)) + ((t4.w + t5.w) + (t6.w + t7.w))) * fn;
        *(float4*)&Sp[0][base] = sv;    // Sl == Sp[0]
    }
    __syncthreads();

    float* Sl = &Sp[0][0];

    // ---- proven epilogue (64 tokens) ----
    if (tid < 64) {
        const int mm = tid;
        float mx = -3.0e38f;
        for (int e = 0; e < NE; e++) mx = fmaxf(mx, Sl[mm * 65 + e]);
        float sum = 0.f;
        for (int e = 0; e < NE; e++) {
            float p = __expf(Sl[mm * 65 + e] - mx);
            Pl[mm * 65 + e] = p;
            sum += p;
        }
        RS[mm] = 1.0f / sum;
    }
    __syncthreads();

    #pragma unroll
    for (int qq = 0; qq < 2; qq++) {    // coalesced probs write: 1024 float4
        int f = tid + 512 * qq;
        int mr = f >> 4;
        int e0 = (f & 15) * 4;
        float rs = RS[mr];
        float4 pv;
        pv.x = Pl[mr * 65 + e0 + 0] * rs;
        pv.y = Pl[mr * 65 + e0 + 1] * rs;
        pv.z = Pl[mr * 65 + e0 + 2] * rs;
        pv.w = Pl[mr * 65 + e0 + 3] * rs;
        *(float4*)&probs[(size_t)(tok0 + mr) * NE + e0] = pv;
    }

    if (tid < 64) {                      // destructive top-4, lowest-index ties
        const int mm = tid;
        float wvv[TOPK]; int idx[TOPK];
        float wsum = 0.f;
        #pragma unroll
        for (int kk = 0; kk < TOPK; ++kk) {
            float best = -3.0e38f; int bi = 0;
            for (int e = 0; e < NE; e++) {
                float v = Sl[mm * 65 + e];
                if (v > best) { best = v; bi = e; }
            }
            Sl[mm * 65 + bi] = -3.4e38f;
            float p = Pl[mm * 65 + bi];
            wvv[kk] = p; idx[kk] = bi; wsum += p;
        }
        float inv = 1.0f / wsum;
        size_t ob = (size_t)(tok0 + mm) * TOPK;
        #pragma unroll
        for (int kk = 0; kk < TOPK; kk++) {
            tkw[ob + kk] = wvv[kk] * inv * pes[idx[kk]];
            tki[ob + kk] = (float)idx[kk];   // harness reads flat buffer as float32
        }
    }
}

extern "C" void kernel_launch(void* const* d_in, const int* in_sizes, int n_in,
                              void* d_out, int out_size, void* d_ws, size_t ws_size,
                              hipStream_t stream) {
    const float* x     = (const float*)d_in[0];
    const float* w     = (const float*)d_in[1];
    const float* scale = (const float*)d_in[2];
    const float* pes   = (const float*)d_in[3];
    const int tokens = in_sizes[0] / HDIM;      // 16384

    float* probs = (float*)d_out;
    float* tkw   = probs + (size_t)tokens * NE;
    float* tki   = tkw + (size_t)tokens * TOPK;

    unsigned short* wtb = (unsigned short*)d_ws;   // 3 planes x 256 KB = 768 KB

    prep_b_kernel<<<HDIM / 32, 256, 0, stream>>>(w, scale, wtb);

    const int grid = tokens / 64;               // 256 -> 1 block/CU
    fused_router_kernel<<<grid, 512, 0, stream>>>(x, wtb, pes, probs, tkw, tki);
}